// Round 7
// baseline (400.579 us; speedup 1.0000x reference)
//
#include <hip/hip_runtime.h>
#include <hip/hip_bf16.h>
#include <cstdint>
#include <cstddef>

// Problem constants
#define B_   64
#define LC_  1024
#define LQ_  128
#define D_   128

typedef __bf16 bf16;
typedef bf16  bf16x8 __attribute__((ext_vector_type(8)));
typedef bf16  bf16x4 __attribute__((ext_vector_type(4)));
typedef float f32x4  __attribute__((ext_vector_type(4)));
typedef short s16x4  __attribute__((ext_vector_type(4)));

__device__ __forceinline__ f32x4 mfma16(bf16x8 a, bf16x8 b, f32x4 c) {
  return __builtin_amdgcn_mfma_f32_16x16x32_bf16(a, b, c, 0, 0, 0);
}
// K=16 bf16 MFMA: A/B = 4 bf16 (2 VGPRs). Layouts: A[m=l15][k=quad*4+e],
// B[k=quad*4+e][n=l15], D[m=quad*4+e][n=l15].
__device__ __forceinline__ f32x4 mfma16k16(s16x4 a, s16x4 b, f32x4 c) {
#if __has_builtin(__builtin_amdgcn_mfma_f32_16x16x16bf16_1k)
  return __builtin_amdgcn_mfma_f32_16x16x16bf16_1k(a, b, c, 0, 0, 0);
#else
  asm("v_mfma_f32_16x16x16_bf16 %0, %1, %2, %0" : "+v"(c) : "v"(a), "v"(b));
  return c;
#endif
}
__device__ __forceinline__ short bfbits(float x) {
  bf16 h = (bf16)x;
  return __builtin_bit_cast(short, h);
}

// XOR swizzle: spreads row-strided column reads across banks (16B granule).
__device__ __forceinline__ int swz(int row, int elem) { return elem ^ ((row & 7) << 3); }

// ---------------------------------------------------------------------------
// kpre = c-path (bx<8) U q-path (bx==8), grid (9, B).
//  c path: cw1[b,k] = c.w1 ; cw3 = bf16(c*w3)      (cT eliminated — k1 v3
//          reads fp32 c directly for its K16 B-fragments)
//  q path: qw2[b,j] = q.w2 ; qb = bf16(q) ; qT = bf16(q)^T
// ---------------------------------------------------------------------------
__global__ __launch_bounds__(256) void kpre(const float* __restrict__ c, const float* __restrict__ q,
                                            const float* __restrict__ w,
                                            float* __restrict__ cw1, bf16* __restrict__ cw3,
                                            float* __restrict__ qw2, bf16* __restrict__ qb,
                                            bf16* __restrict__ qT) {
  __shared__ float wA[128];
  __shared__ float wB[128];
  __shared__ bf16  tile[128 * 136];
  const int b = blockIdx.y, bx = blockIdx.x;
  const int t = threadIdx.x;

  if (bx < 8) {
    // ---------------- c path: 128-row k-slice, pure streaming ----------------
    const int k0 = bx * 128;
    if (t < 128) { wA[t] = w[t]; wB[t] = w[256 + t]; }
    __syncthreads();
    const int r = t >> 1, d0 = (t & 1) * 64;
    const float* crow = c + ((size_t)(b * LC_ + k0 + r) * D_ + d0);
    bf16* orow = cw3 + ((size_t)(b * LC_ + k0 + r) * D_ + d0);
    float dot = 0.f;
#pragma unroll
    for (int v = 0; v < 8; ++v) {
      const float4 f0 = ((const float4*)crow)[v * 2 + 0];
      const float4 f1 = ((const float4*)crow)[v * 2 + 1];
      const int dd = d0 + v * 8;
      dot += f0.x * wA[dd + 0] + f0.y * wA[dd + 1] + f0.z * wA[dd + 2] + f0.w * wA[dd + 3]
           + f1.x * wA[dd + 4] + f1.y * wA[dd + 5] + f1.z * wA[dd + 6] + f1.w * wA[dd + 7];
      bf16x8 o;
      o[0] = (bf16)(f0.x * wB[dd + 0]); o[1] = (bf16)(f0.y * wB[dd + 1]);
      o[2] = (bf16)(f0.z * wB[dd + 2]); o[3] = (bf16)(f0.w * wB[dd + 3]);
      o[4] = (bf16)(f1.x * wB[dd + 4]); o[5] = (bf16)(f1.y * wB[dd + 5]);
      o[6] = (bf16)(f1.z * wB[dd + 6]); o[7] = (bf16)(f1.w * wB[dd + 7]);
      *(bf16x8*)(orow + v * 8) = o;
    }
    dot += __shfl_xor(dot, 1);
    if ((t & 1) == 0) cw1[b * LC_ + k0 + r] = dot;
  } else {
    // ---------------- q path: whole batch ----------------
    if (t < 128) wA[t] = w[128 + t];
    __syncthreads();
    {
      const int r = t >> 1, d0 = (t & 1) * 64;
      const float* qrow = q + ((size_t)(b * LQ_ + r) * D_ + d0);
      bf16* orow = qb + ((size_t)(b * LQ_ + r) * D_ + d0);
      float dot = 0.f;
#pragma unroll
      for (int v = 0; v < 8; ++v) {
        const float4 f0 = ((const float4*)qrow)[v * 2 + 0];
        const float4 f1 = ((const float4*)qrow)[v * 2 + 1];
        const int dd = d0 + v * 8;
        dot += f0.x * wA[dd + 0] + f0.y * wA[dd + 1] + f0.z * wA[dd + 2] + f0.w * wA[dd + 3]
             + f1.x * wA[dd + 4] + f1.y * wA[dd + 5] + f1.z * wA[dd + 6] + f1.w * wA[dd + 7];
        bf16x8 o;
        o[0] = (bf16)f0.x; o[1] = (bf16)f0.y; o[2] = (bf16)f0.z; o[3] = (bf16)f0.w;
        o[4] = (bf16)f1.x; o[5] = (bf16)f1.y; o[6] = (bf16)f1.z; o[7] = (bf16)f1.w;
        *(bf16x8*)&tile[r * 136 + dd] = o;
        *(bf16x8*)(orow + v * 8) = o;
      }
      dot += __shfl_xor(dot, 1);
      if ((t & 1) == 0) qw2[b * LQ_ + r] = dot;
    }
    __syncthreads();
    {
      const int d = t >> 1, jh = (t & 1) * 64;
      bf16* trow = qT + ((size_t)(b * D_ + d) * LQ_ + jh);
#pragma unroll
      for (int v = 0; v < 8; ++v) {
        bf16x8 o;
#pragma unroll
        for (int e = 0; e < 8; ++e) o[e] = tile[(jh + v * 8 + e) * 136 + d];
        *(bf16x8*)(trow + v * 8) = o;
      }
    }
  }
}

// ---------------------------------------------------------------------------
// K1 v3: per (b, ks 0..7, js 0..3): 128 k-rows x 32 j. 4 waves; each wave owns
// a 16-row k-slice per 64-row k-tile. GEMM1 (K32): S[k][j] with cw3 direct
// global A-frags + swizzled q LDS B-frags. exp -> P stays IN REGISTERS: the
// GEMM1 C-layout P[k=quad*4+rr][j=l15] IS the K16 A-frag layout for output
// rows j. GEMM2 (K16): each wave sums only its own 16 k-rows; B-frags
// bf16(c[k][d]) loaded directly from fp32 c (base + immediate offsets).
// ZERO barriers in the k-loop. Cross-wave k-sum via one LDS-atomic reduce at
// block end.  Tpart[(b,ks)][j][d] fp32 partials ; lpart[(b,ks)][j].
// ---------------------------------------------------------------------------
__global__ __launch_bounds__(256, 4) void k1(const float* __restrict__ cw1, const float* __restrict__ qw2,
                                             const int* __restrict__ cmask,
                                             const bf16* __restrict__ cw3, const float* __restrict__ c,
                                             const bf16* __restrict__ qb,
                                             float* __restrict__ Tpart, float* __restrict__ lpart) {
  // union: loop phase qs[32][128] bf16 = 8KB ; end phase Tsum[32][128] f32 = 16KB
  __shared__ __align__(16) char smem[16384 + 512];
  bf16*  qs   = (bf16*)smem;             // [j][d] swizzled
  float* Tsum = (float*)smem;            // end-phase union (qs dead by then)
  float* lred = (float*)(smem + 16384);  // [4 wk][32 j]
  const int bx = blockIdx.x;
  const int ks = bx >> 2, js = bx & 3;
  const int b = blockIdx.y;
  const int j0 = js * 32;
  const int t = threadIdx.x;
  const int wk = t >> 6, lane = t & 63, quad = lane >> 4, l15 = lane & 15;

  // stage 32 q rows once (swizzled)
#pragma unroll
  for (int idx = t; idx < 512; idx += 256) {
    const int row = idx >> 4, ch = idx & 15;
    *(bf16x8*)&qs[row * 128 + swz(row, ch * 8)] =
        *(const bf16x8*)(qb + ((size_t)(b * LQ_ + j0 + row) * D_ + ch * 8));
  }
  const f32x4 z = {0.f, 0.f, 0.f, 0.f};
  f32x4 Tacc[2][8];
#pragma unroll
  for (int jt = 0; jt < 2; ++jt)
#pragma unroll
    for (int dt = 0; dt < 8; ++dt) Tacc[jt][dt] = z;
  float lacc[2] = {0.f, 0.f};
  float qv[2];
#pragma unroll
  for (int jt = 0; jt < 2; ++jt) qv[jt] = qw2[b * LQ_ + j0 + jt * 16 + l15];
  __syncthreads();

  for (int kt = 0; kt < 2; ++kt) {
    const int krow_base = ks * 128 + kt * 64 + wk * 16;   // this wave's 16 k-rows

    // GEMM1 (K32): S[k=quad*4+rr][j=jt*16+l15]
    f32x4 S[2] = {z, z};
#pragma unroll
    for (int kk = 0; kk < 4; ++kk) {
      const bf16x8 a = *(const bf16x8*)(cw3 +
          ((size_t)(b * LC_ + krow_base + l15) * D_ + kk * 32 + quad * 8));
#pragma unroll
      for (int jt = 0; jt < 2; ++jt) {
        const int jr = jt * 16 + l15;
        const bf16x8 bq = *(const bf16x8*)&qs[jr * 128 + swz(jr, kk * 32 + quad * 8)];
        S[jt] = mfma16(a, bq, S[jt]);
      }
    }
    // exp -> pk (already in K16 A-frag layout: A[m=j=l15][k=quad*4+rr])
    float c1v[4]; int cmv[4];
#pragma unroll
    for (int rr = 0; rr < 4; ++rr) {
      const int krow = krow_base + quad * 4 + rr;
      c1v[rr] = cw1[b * LC_ + krow];
      cmv[rr] = cmask[b * LC_ + krow];
    }
    s16x4 pk[2];
#pragma unroll
    for (int jt = 0; jt < 2; ++jt)
#pragma unroll
      for (int rr = 0; rr < 4; ++rr) {
        const float p = cmv[rr] ? 0.f : __expf(S[jt][rr] + c1v[rr] + qv[jt]);
        lacc[jt] += p;
        pk[jt][rr] = bfbits(p);
      }
    // GEMM2 (K16): T[j][d] += P^T(own 16 k) @ c ; B-frag straight from fp32 c
    const float* crow0 = c + ((size_t)(b * LC_ + krow_base + quad * 4) * D_ + l15);
#pragma unroll
    for (int dt = 0; dt < 8; ++dt) {
      s16x4 bd;
#pragma unroll
      for (int e = 0; e < 4; ++e) bd[e] = bfbits(crow0[e * D_ + dt * 16]);
      Tacc[0][dt] = mfma16k16(pk[0], bd, Tacc[0][dt]);
      Tacc[1][dt] = mfma16k16(pk[1], bd, Tacc[1][dt]);
    }
  }

  // l_j partial: quad-reduce in-wave, cross-wave via lred
#pragma unroll
  for (int jt = 0; jt < 2; ++jt) {
    lacc[jt] += __shfl_xor(lacc[jt], 16);
    lacc[jt] += __shfl_xor(lacc[jt], 32);
  }
  if (lane < 16) {
#pragma unroll
    for (int jt = 0; jt < 2; ++jt) lred[wk * 32 + jt * 16 + l15] = lacc[jt];
  }
  __syncthreads();   // lred ready; qs dead -> Tsum region reusable
  if (t < 32)
    lpart[(size_t)(b * 8 + ks) * 128 + j0 + t] =
        lred[0 * 32 + t] + lred[1 * 32 + t] + lred[2 * 32 + t] + lred[3 * 32 + t];

  // cross-wave k-sum: zero Tsum, LDS-atomic deposit, write global
#pragma unroll
  for (int idx = t; idx < 1024; idx += 256) ((f32x4*)Tsum)[idx] = z;
  __syncthreads();
#pragma unroll
  for (int jt = 0; jt < 2; ++jt)
#pragma unroll
    for (int dt = 0; dt < 8; ++dt)
#pragma unroll
      for (int rr = 0; rr < 4; ++rr)
        atomicAdd(&Tsum[(jt * 16 + quad * 4 + rr) * 128 + dt * 16 + l15], Tacc[jt][dt][rr]);
  __syncthreads();
  float* tp = Tpart + ((size_t)(b * 8 + ks)) * (128 * 128) + (size_t)j0 * 128;
#pragma unroll
  for (int idx = t; idx < 1024; idx += 256)
    ((float4*)tp)[idx] = ((const float4*)Tsum)[idx];
}

// ---------------------------------------------------------------------------
// K1r: reduce the eight k-partials, normalize by l_j, emit TT = bf16(T)^T.
// ---------------------------------------------------------------------------
__global__ __launch_bounds__(512) void k1r(const float* __restrict__ Tpart,
                                           const float* __restrict__ lpart,
                                           bf16* __restrict__ TT) {
  __shared__ float Tsum[32 * 132];
  __shared__ float linv[32];
  const int js = blockIdx.x, b = blockIdx.y;
  const int j0 = js * 32;
  const int t = threadIdx.x;
#pragma unroll
  for (int idx = t; idx < 1024; idx += 512) {
    const int row = idx >> 5, seg = idx & 31;
    float4 s = {0.f, 0.f, 0.f, 0.f};
#pragma unroll
    for (int i = 0; i < 8; ++i) {
      const float4 v = ((const float4*)(Tpart + ((size_t)(b * 8 + i)) * (128 * 128)) + j0 * 32)[idx];
      s.x += v.x; s.y += v.y; s.z += v.z; s.w += v.w;
    }
    *(float4*)&Tsum[row * 132 + seg * 4] = s;
  }
  if (t < 32) {
    float l = 0.f;
#pragma unroll
    for (int i = 0; i < 8; ++i) l += lpart[(size_t)(b * 8 + i) * 128 + j0 + t];
    linv[t] = 1.f / l;
  }
  __syncthreads();
  if (t < 256) {
    const int d = t >> 1, jhh = (t & 1) * 16;
    bf16x8 o0, o1;
#pragma unroll
    for (int e = 0; e < 8; ++e) {
      o0[e] = (bf16)(Tsum[(jhh + e) * 132 + d] * linv[jhh + e]);
      o1[e] = (bf16)(Tsum[(jhh + 8 + e) * 132 + d] * linv[jhh + 8 + e]);
    }
    bf16* dst = TT + ((size_t)(b * D_ + d) * LQ_ + j0 + jhh);
    *(bf16x8*)dst = o0;
    *(bf16x8*)(dst + 8) = o1;
  }
}

// ---------------------------------------------------------------------------
// K2 v4: = v3 with the per-jtl barriers REMOVED (P1 regions are wave-private;
// per-wave DS ordering guarantees the write->read). Barriers remain only
// around the shared qTs/TTs staging and the epilogue LDS union.
// ---------------------------------------------------------------------------
__global__ __launch_bounds__(256, 4) void k2(const float* __restrict__ c, const float* __restrict__ cw1,
                                             const float* __restrict__ qw2, const int* __restrict__ qmask,
                                             const bf16* __restrict__ cw3, const bf16* __restrict__ qb,
                                             const bf16* __restrict__ qT, const bf16* __restrict__ TT,
                                             float* __restrict__ out) {
  // union LDS: loop phase qTs/TTs/P1 = 37888 B ; epilogue A32/B32 = 33792 B
  __shared__ __align__(16) char smem[37888];
  bf16* qTs = (bf16*)(smem);             // [128][64] swizzled, current j-half
  bf16* TTs = (bf16*)(smem + 16384);     // [128][64] swizzled, current j-half
  bf16* P1  = (bf16*)(smem + 32768);     // [64][40]  wave-private rows
  float* A32 = (float*)(smem);           // [32][132] epilogue
  float* B32 = (float*)(smem + 16896);   // [32][132] epilogue
  const int it = blockIdx.x, b = blockIdx.y;
  const int i0 = it * 64;
  const int t = threadIdx.x;
  const int w = t >> 6, lane = t & 63, quad = lane >> 4, l15 = lane & 15;

  bf16x8 aF[4];
#pragma unroll
  for (int kk = 0; kk < 4; ++kk)
    aF[kk] = *(const bf16x8*)(cw3 +
        ((size_t)(b * LC_ + i0 + w * 16 + l15) * D_ + kk * 32 + quad * 8));
  float c1v[4];
#pragma unroll
  for (int rr = 0; rr < 4; ++rr)
    c1v[rr] = cw1[b * LC_ + i0 + w * 16 + quad * 4 + rr];

  const f32x4 z = {0.f, 0.f, 0.f, 0.f};
  f32x4 Aacc[8], Bacc[8];
#pragma unroll
  for (int n = 0; n < 8; ++n) { Aacc[n] = z; Bacc[n] = z; }
  float lacc[4] = {0.f, 0.f, 0.f, 0.f};

#pragma unroll
  for (int jh = 0; jh < 2; ++jh) {
    if (jh) __syncthreads();   // all waves done reading previous qTs/TTs
#pragma unroll
    for (int idx = t; idx < 1024; idx += 256) {
      const int row = idx >> 3, ch = idx & 7;
      const int sc = (ch * 8) ^ ((row & 7) << 3);
      *(bf16x8*)&qTs[row * 64 + sc] =
          *(const bf16x8*)(qT + ((size_t)(b * D_ + row) * LQ_ + jh * 64 + ch * 8));
      *(bf16x8*)&TTs[row * 64 + sc] =
          *(const bf16x8*)(TT + ((size_t)(b * D_ + row) * LQ_ + jh * 64 + ch * 8));
    }
    __syncthreads();

#pragma unroll
    for (int jtl = 0; jtl < 2; ++jtl) {
      const int j0 = jh * 64 + jtl * 32;
      const float qv0 = qw2[b * LQ_ + j0 + l15];
      const float qv1 = qw2[b * LQ_ + j0 + 16 + l15];
      const int   qm0 = qmask[b * LQ_ + j0 + l15];
      const int   qm1 = qmask[b * LQ_ + j0 + 16 + l15];

      f32x4 S0 = z, S1 = z;
#pragma unroll
      for (int kk = 0; kk < 4; ++kk) {
        const bf16x8 b0 = *(const bf16x8*)(qb +
            ((size_t)(b * LQ_ + j0 + l15) * D_ + kk * 32 + quad * 8));
        const bf16x8 b1 = *(const bf16x8*)(qb +
            ((size_t)(b * LQ_ + j0 + 16 + l15) * D_ + kk * 32 + quad * 8));
        S0 = mfma16(aF[kk], b0, S0);
        S1 = mfma16(aF[kk], b1, S1);
      }
#pragma unroll
      for (int rr = 0; rr < 4; ++rr) {
        const float p0 = qm0 ? 0.f : __expf(S0[rr] + c1v[rr] + qv0);
        const float p1 = qm1 ? 0.f : __expf(S1[rr] + c1v[rr] + qv1);
        lacc[rr] += p0 + p1;
        P1[(w * 16 + quad * 4 + rr) * 40 + l15] = (bf16)p0;
        P1[(w * 16 + quad * 4 + rr) * 40 + 16 + l15] = (bf16)p1;
      }
      // no barrier: P1 rows [w*16, w*16+16) are wave-private; DS is in-order
      const bf16x8 aP = *(bf16x8*)&P1[(w * 16 + l15) * 40 + quad * 8];
      const int cbase = jtl * 32 + quad * 8;
#pragma unroll
      for (int nt = 0; nt < 8; ++nt) {
        const int row = nt * 16 + l15;
        const int sc = cbase ^ ((row & 7) << 3);
        const bf16x8 bq = *(bf16x8*)&qTs[row * 64 + sc];
        const bf16x8 bt = *(bf16x8*)&TTs[row * 64 + sc];
        Aacc[nt] = mfma16(aP, bq, Aacc[nt]);
        Bacc[nt] = mfma16(aP, bt, Bacc[nt]);
      }
      // no barrier: next jtl only rewrites this wave's own P1 rows
    }
  }

#pragma unroll
  for (int rr = 0; rr < 4; ++rr) {
    float v = lacc[rr];
    v += __shfl_xor(v, 1); v += __shfl_xor(v, 2);
    v += __shfl_xor(v, 4); v += __shfl_xor(v, 8);
    lacc[rr] = 1.f / v;
  }

  __syncthreads();   // all waves done with qTs/TTs before epilogue LDS reuse
#pragma unroll
  for (int h = 0; h < 2; ++h) {
    if ((w >> 1) == h) {
      const int lrow0 = (w & 1) * 16 + quad * 4;
#pragma unroll
      for (int nt = 0; nt < 8; ++nt)
#pragma unroll
        for (int rr = 0; rr < 4; ++rr) {
          A32[(lrow0 + rr) * 132 + nt * 16 + l15] = Aacc[nt][rr] * lacc[rr];
          B32[(lrow0 + rr) * 132 + nt * 16 + l15] = Bacc[nt][rr] * lacc[rr];
        }
    }
    __syncthreads();
#pragma unroll
    for (int idx = t; idx < 1024; idx += 256) {
      const int lrow = idx >> 5, seg = idx & 31;
      const size_t grow = (size_t)(b * LC_ + i0 + h * 32 + lrow);
      const float4 c4 = ((const float4*)(c + grow * D_))[seg];
      const float4 a4 = *(float4*)&A32[lrow * 132 + seg * 4];
      const float4 b4 = *(float4*)&B32[lrow * 132 + seg * 4];
      float4* ob = (float4*)(out + grow * 512);
      ob[seg] = c4;
      ob[32 + seg] = a4;
      float4 ca; ca.x = c4.x * a4.x; ca.y = c4.y * a4.y; ca.z = c4.z * a4.z; ca.w = c4.w * a4.w;
      ob[64 + seg] = ca;
      float4 cb; cb.x = c4.x * b4.x; cb.y = c4.y * b4.y; cb.z = c4.z * b4.z; cb.w = c4.w * b4.w;
      ob[96 + seg] = cb;
    }
    __syncthreads();
  }
}

// ---------------------------------------------------------------------------
extern "C" void kernel_launch(void* const* d_in, const int* in_sizes, int n_in,
                              void* d_out, int out_size, void* d_ws, size_t ws_size,
                              hipStream_t stream) {
  (void)in_sizes; (void)n_in; (void)out_size; (void)ws_size;
  const float* c     = (const float*)d_in[0];
  const float* q     = (const float*)d_in[1];
  const int*   cmask = (const int*)d_in[2];
  const int*   qmask = (const int*)d_in[3];
  const float* w     = (const float*)d_in[4];
  float* out = (float*)d_out;

  // workspace layout (23.3 MB; cT eliminated)
  char* ws = (char*)d_ws;
  float* cw1 = (float*)(ws + 0);          //  64*1024 f32
  float* qw2 = (float*)(ws + 262144);     //  64*128  f32
  bf16*  cw3 = (bf16*)(ws + 294912);      //  64*1024*128 bf16  (c*w3)
  bf16*  qb  = (bf16*)(ws + 17072128);    //  64*128*128 bf16
  bf16*  qT  = (bf16*)(ws + 19169280);    //  64*128*128 bf16  (q transposed)
  bf16*  TT  = (bf16*)(ws + 21266432);    //  64*128*128 bf16  (T transposed)

  // k-split partials live in d_out scratch (fully overwritten by k2 afterwards)
  float* Tpart = out;                     //  64*8*128*128 f32 = 33.6 MB
  float* lpart = out + 8388608;           //  64*8*128 f32

  kpre<<<dim3(9, 64), 256, 0, stream>>>(c, q, w, cw1, cw3, qw2, qb, qT);
  k1  <<<dim3(32, 64), 256, 0, stream>>>(cw1, qw2, cmask, cw3, c, qb, Tpart, lpart);
  k1r <<<dim3(4, 64), 512, 0, stream>>>(Tpart, lpart, TT);
  k2  <<<dim3(16, 64), 256, 0, stream>>>(c, cw1, qw2, qmask, cw3, qb, qT, TT, out);
}